// Round 12
// baseline (166.452 us; speedup 1.0000x reference)
//
#include <hip/hip_runtime.h>
#include <hip/hip_bf16.h>
#include <stdint.h>

typedef unsigned short u16;
typedef unsigned int u32;
typedef __bf16 bf16x8 __attribute__((ext_vector_type(8)));
typedef float f32x4 __attribute__((ext_vector_type(4)));
typedef float f32x16 __attribute__((ext_vector_type(16)));
typedef u32 u32x4 __attribute__((ext_vector_type(4)));

#define AS1 __attribute__((address_space(1)))
#define AS3 __attribute__((address_space(3)))

// async global->LDS, 16B per lane; LDS dest = wave-uniform base + lane*16.
__device__ __forceinline__ void async16(const u16* g, u16* l) {
  __builtin_amdgcn_global_load_lds((const AS1 uint32_t*)(const void*)g,
                                   (AS3 uint32_t*)l, 16, 0, 0);
}

__device__ __forceinline__ u16 f2bf(float v) {
  union { __hip_bfloat16 b; u16 u; } c; c.b = __float2bfloat16(v); return c.u;
}

// hardware packed f32->bf16 (RNE), one VALU op per pair (T12)
__device__ __forceinline__ u32 pkbf(float a, float b) {
  u32 r;
  asm("v_cvt_pk_bf16_f32 %0, %1, %2" : "=v"(r) : "v"(a), "v"(b));
  return r;
}

// v_permlane32_swap_b32: a[32:63] <-> b[0:31]
__device__ __forceinline__ void swap32(u32 &a, u32 &b) {
  asm("v_permlane32_swap_b32 %0, %1" : "+v"(a), "+v"(b));
}

// raw v_exp_f32 — args here are in [-45,-15]: results normal, no OCML wrapper.
#if __has_builtin(__builtin_amdgcn_exp2f)
#define fast_exp2(x) __builtin_amdgcn_exp2f(x)
#else
#define fast_exp2(x) exp2f(x)
#endif

#if __has_builtin(__builtin_amdgcn_rcpf)
#define fast_rcp(x) __builtin_amdgcn_rcpf(x)
#else
#define fast_rcp(x) (1.0f / (x))
#endif

__device__ __forceinline__ uint4 pack8(float4 lo, float4 hi) {
  uint4 q;
  q.x = (u32)f2bf(lo.x) | ((u32)f2bf(lo.y) << 16);
  q.y = (u32)f2bf(lo.z) | ((u32)f2bf(lo.w) << 16);
  q.z = (u32)f2bf(hi.x) | ((u32)f2bf(hi.y) << 16);
  q.w = (u32)f2bf(hi.z) | ((u32)f2bf(hi.w) << 16);
  return q;
}

// ---------------- prep: fused {x cvt} + {Wqkv^T, Wout^T} ------------------
// (Round-8 version — passing.)
__global__ void prep(const float* __restrict__ x, u16* __restrict__ xb,
                     const float* __restrict__ Wqkv, u16* __restrict__ WqkvT,
                     const float* __restrict__ Wout, u16* __restrict__ WoutT) {
  const int tx = threadIdx.x, ty = threadIdx.y, z = blockIdx.z;
  if (z >= 2) {
    const int cid = (z - 2) * 256 + blockIdx.y * 16 + blockIdx.x;
    const int t = ty * 16 + tx;
    const int i = (cid * 256 + t) * 8;
    float4 lo = *(const float4*)(x + i);
    float4 hi = *(const float4*)(x + i + 4);
    *(uint4*)(xb + i) = pack8(lo, hi);
    return;
  }
  const float* in = z ? Wout : Wqkv;
  u16* out = z ? WoutT : WqkvT;
  __shared__ u16 tile[64][65];
  const int c0 = blockIdx.x * 64, r0 = blockIdx.y * 64;
#pragma unroll
  for (int i = 0; i < 4; i++) {
    const int row = r0 + ty + i * 16;
    float4 v = *(const float4*)&in[(size_t)row * 1024 + c0 + tx * 4];
    tile[tx * 4 + 0][ty + i * 16] = f2bf(v.x);
    tile[tx * 4 + 1][ty + i * 16] = f2bf(v.y);
    tile[tx * 4 + 2][ty + i * 16] = f2bf(v.z);
    tile[tx * 4 + 3][ty + i * 16] = f2bf(v.w);
  }
  __syncthreads();
#pragma unroll
  for (int i = 0; i < 4; i++) {
    const int orow = c0 + ty + i * 16;
    u32 w0 = (u32)tile[ty + i * 16][tx * 4 + 0] | ((u32)tile[ty + i * 16][tx * 4 + 1] << 16);
    u32 w1 = (u32)tile[ty + i * 16][tx * 4 + 2] | ((u32)tile[ty + i * 16][tx * 4 + 3] << 16);
    uint2 pk = {w0, w1};
    *(uint2*)&out[(size_t)orow * 1024 + r0 + tx * 4] = pk;
  }
}

// ---------------- build Vt[b][h][d][j] = mask[b][j] ? 0 : w[b,j][h*64+d] --
// (Round-8 version — passing.)
__global__ void scale_transpose_v(const u16* __restrict__ w, const int* __restrict__ mask,
                                  u16* __restrict__ Vt) {
  __shared__ u16 tile[64][65];
  const int tx = threadIdx.x, ty = threadIdx.y;
  const int j0 = blockIdx.x * 64;
  const int bh = blockIdx.z, b = bh >> 4, hc = (bh & 15) * 64;
#pragma unroll
  for (int i = 0; i < 4; i++) {
    const int j = j0 + ty + i * 16;
    uint2 v = *(const uint2*)&w[(size_t)(b * 2048 + j) * 1024 + hc + tx * 4];
    if (mask[b * 2048 + j]) { v.x = 0u; v.y = 0u; }
    tile[tx * 4 + 0][ty + i * 16] = (u16)(v.x & 0xFFFF);
    tile[tx * 4 + 1][ty + i * 16] = (u16)(v.x >> 16);
    tile[tx * 4 + 2][ty + i * 16] = (u16)(v.y & 0xFFFF);
    tile[tx * 4 + 3][ty + i * 16] = (u16)(v.y >> 16);
  }
  __syncthreads();
#pragma unroll
  for (int i = 0; i < 4; i++) {
    const int d = ty + i * 16;
    u32 w0 = (u32)tile[d][tx * 4 + 0] | ((u32)tile[d][tx * 4 + 1] << 16);
    u32 w1 = (u32)tile[d][tx * 4 + 2] | ((u32)tile[d][tx * 4 + 3] << 16);
    uint2 pk = {w0, w1};
    *(uint2*)&Vt[((size_t)bh * 64 + d) * 2048 + j0 + tx * 4] = pk;
  }
}

// ---------------- GEMM: C(MxN) = A(MxK) * BT(NxK)^T  [+bias], bf16 A/B ----
// (REVERTED to round-8 64x64 version — best measured config. r11's 128x128
// reg-blocked variant ran at 1 block/CU = 1 wave/SIMD and was net worse.)
template<bool OUT_F32>
__launch_bounds__(256)
__global__ void gemm_bt(const u16* __restrict__ A, const u16* __restrict__ BT,
                        void* __restrict__ Cp, const float* __restrict__ bias,
                        int M, int N, int K) {
  __shared__ __align__(16) u16 As[2][64 * 64];    // 16 KB
  __shared__ __align__(16) u16 Bs[2][64 * 64];    // 16 KB
  const int t = threadIdx.x;
  const int lane = t & 63, wave = t >> 6;
  const int ql = lane & 31, hi = lane >> 5, swz = ql & 7;
  const int wgid = blockIdx.x + gridDim.x * blockIdx.y;
  const int c = wgid & 7, ii = wgid >> 3;
  const int m0 = (c * 8 + (ii & 7)) * 64;
  const int n0 = (ii >> 3) * 64;
  const int wm = (wave & 1) * 32, wn = (wave >> 1) * 32;

  f32x16 acc = {};

  const int sr = t >> 3;
  const int sc8 = ((t & 7) ^ (sr & 7)) * 8;
  const u16* gAt = A + (size_t)(m0 + sr) * K + sc8;
  const u16* gBt = BT + (size_t)(n0 + sr) * K + sc8;

#define GSTAGE(buf, k0s) do { \
    async16(gAt + (k0s),                   &As[buf][t * 8]); \
    async16(gAt + (k0s) + (size_t)32 * K,  &As[buf][t * 8 + 2048]); \
    async16(gBt + (k0s),                   &Bs[buf][t * 8]); \
    async16(gBt + (k0s) + (size_t)32 * K,  &Bs[buf][t * 8 + 2048]); \
  } while (0)

  GSTAGE(0, 0);

  int cur = 0;
  for (int k0 = 0; k0 < K; k0 += 64) {
    if (k0 + 64 < K) {
      GSTAGE(cur ^ 1, k0 + 64);
      asm volatile("s_waitcnt vmcnt(4)" ::: "memory");
    } else {
      asm volatile("s_waitcnt vmcnt(0)" ::: "memory");
    }
    __builtin_amdgcn_s_barrier();
    __builtin_amdgcn_sched_barrier(0);   // rule #18

#pragma unroll
    for (int kk = 0; kk < 4; kk++) {
      bf16x8 af = *(const bf16x8*)&As[cur][(wm + ql) * 64 + (((2 * kk + hi) ^ swz) * 8)];
      bf16x8 bfr = *(const bf16x8*)&Bs[cur][(wn + ql) * 64 + (((2 * kk + hi) ^ swz) * 8)];
      acc = __builtin_amdgcn_mfma_f32_32x32x16_bf16(af, bfr, acc, 0, 0, 0);
    }
    asm volatile("s_waitcnt lgkmcnt(0)" ::: "memory");
    __builtin_amdgcn_sched_barrier(0);
    __builtin_amdgcn_s_barrier();
    __builtin_amdgcn_sched_barrier(0);
    cur ^= 1;
  }
#undef GSTAGE

  const float bv = bias ? bias[n0 + wn + ql] : 0.f;
  const int col = n0 + wn + ql;

#pragma unroll
  for (int r = 0; r < 16; r++) {
    const int row = m0 + wm + (r & 3) + 8 * (r >> 2) + 4 * hi;
    const size_t ci = (size_t)row * N + col;
    const float v = acc[r] + bv;
    if (OUT_F32) ((float*)Cp)[ci] = v;
    else ((u16*)Cp)[ci] = f2bf(v);
  }
}

// ---------------- fused attention per (b,h) -------------------------------
// ROUND 12: 4-way split-K for occupancy. r9's mistake: it shrank LDS but kept
// grid=512 (hard cap 2 blocks/CU = 16 waves). Now: grid = 32bh x 32 q-chunks
// = 1024 blocks x 512 thr; waves = 2 qg (32 q-rows) x 4 kgr (512 keys);
// LDS = 4kgr x 2buf x (4KB K + 4KB V) = 64KB -> 2 blocks/CU = 32 waves/CU
// (2x round-8). KVBLK=32 inner loop transplanted verbatim from r9 (passed).
// 16 iterations (512/32) = same barrier count as round-8. 4-way LDS merge.
#define C1 0.18033688f      // 0.125 * log2(e)
#define C2 -28.853901f      // -20 * log2(e)
__launch_bounds__(512)
__global__ void attn_kernel(const u16* __restrict__ w, const u16* __restrict__ Vt,
                            u16* __restrict__ y) {
  __shared__ __align__(16) u16 Ks[4][2][32 * 64];   // [kgr][buf][key][d] 32KB
  __shared__ __align__(16) u16 Vs[4][2][64 * 32];   // [kgr][buf][d][key] 32KB
  const int t = threadIdx.x, lane = t & 63, wv = t >> 6;
  const int qg = wv & 1, kgr = wv >> 1;             // 2 qg x 4 kgr
  const int ql = lane & 31, hi = lane >> 5, swz = ql & 7, vswz = ql & 3;
  // XCD swizzle (bijective, 1024 blocks): XCD k gets newid [128k,128k+128) = 4 bh
  const int wgid = blockIdx.x + 32 * blockIdx.y;    // grid (32,32)
  const int newid = (wgid & 7) * 128 + (wgid >> 3);
  const int bh = newid >> 5, b = bh >> 4, hc = (bh & 15) * 64;
  const int q0 = (newid & 31) * 64;
  const size_t rowb = (size_t)b * 2048;

  // staging: thread t covers kgroups {t>>8, (t>>8)+2} for both K and V.
  // K slot s=t&255: row=s>>3 (32 keys), chunk=s&7, XOR row&7 (rule 21).
  // V slot s: d=s>>2 (64), chunk=s&3, XOR d&3.
  const int sA = t & 255;
  const int kgA = t >> 8, kgB = kgA + 2;
  const int rowK = sA >> 3;
  const int chK = ((sA & 7) ^ (rowK & 7)) * 8;
  const int dV = sA >> 2;
  const int chV = ((sA & 3) ^ (dV & 3)) * 8;
  const u16* kptr = w + rowb * 1024 + hc;
  const u16* vptr = Vt + (size_t)bh * 64 * 2048;

  // Q fragments (B-operand): lane holds Q[q=ql][d = ks*16 + hi*8 + e]
  bf16x8 qf[4];
  {
    const size_t qrow = rowb + q0 + qg * 32 + ql;
#pragma unroll
    for (int ks = 0; ks < 4; ks++)
      qf[ks] = *(const bf16x8*)&w[qrow * 1024 + hc + ks * 16 + hi * 8];
  }

  union { u32x4 u; bf16x8 bf; } ones;
  ones.u = (u32x4){0x3F803F80u, 0x3F803F80u, 0x3F803F80u, 0x3F803F80u};

  f32x16 o0 = {}, o1 = {};     // O[q][d0..31], O[q][d32..63] (partial: 512 keys)
  f32x16 den = {};             // row denominators (partial)

#define STAGE(buf, j0s) do { \
    async16(kptr + (size_t)(kgA * 512 + (j0s) + rowK) * 1024 + chK, &Ks[kgA][buf][sA * 8]); \
    async16(kptr + (size_t)(kgB * 512 + (j0s) + rowK) * 1024 + chK, &Ks[kgB][buf][sA * 8]); \
    async16(vptr + (size_t)dV * 2048 + kgA * 512 + (j0s) + chV,     &Vs[kgA][buf][sA * 8]); \
    async16(vptr + (size_t)dV * 2048 + kgB * 512 + (j0s) + chV,     &Vs[kgB][buf][sA * 8]); \
  } while (0)

  STAGE(0, 0);
  __syncthreads();

  int cur = 0;
  for (int j0 = 0; j0 < 512; j0 += 32) {
    if (j0 + 32 < 512) STAGE(cur ^ 1, j0 + 32);    // prefetch overlaps compute

    const u16* Wt = Ks[kgr][cur];
    const u16* Vts = Vs[kgr][cur];

    // swapped QK^T (r9-verified): D[key][q], q=lane&31, key=(r&3)+8*(r>>2)+4*hi
    f32x16 p = {};
#pragma unroll
    for (int ks = 0; ks < 4; ks++) {
      bf16x8 af = *(const bf16x8*)&Wt[ql * 64 + (((ks * 2 + hi) ^ swz) * 8)];
      p = __builtin_amdgcn_mfma_f32_32x32x16_bf16(af, qf[ks], p, 0, 0, 0);
    }
    float e[16];
#pragma unroll
    for (int r = 0; r < 16; r++)
      e[r] = fast_exp2(fmaf(p[r], C1, C2));
    u32 a0 = pkbf(e[0], e[1]),   b0 = pkbf(e[4], e[5]);   swap32(a0, b0);
    u32 a1 = pkbf(e[2], e[3]),   b1 = pkbf(e[6], e[7]);   swap32(a1, b1);
    u32 a2 = pkbf(e[8], e[9]),   b2 = pkbf(e[12], e[13]); swap32(a2, b2);
    u32 a3 = pkbf(e[10], e[11]), b3 = pkbf(e[14], e[15]); swap32(a3, b3);
    u32x4 pa0 = {a0, a1, b0, b1};   // P keys 0-15
    u32x4 pa1 = {a2, a3, b2, b3};   // P keys 16-31

    __builtin_amdgcn_s_setprio(1);
    {
      union { u32x4 u; bf16x8 bf; } c0, c1; c0.u = pa0; c1.u = pa1;
      bf16x8 v00 = *(const bf16x8*)&Vts[ql * 32 + ((hi ^ vswz) * 8)];
      bf16x8 v01 = *(const bf16x8*)&Vts[(32 + ql) * 32 + ((hi ^ vswz) * 8)];
      bf16x8 v10 = *(const bf16x8*)&Vts[ql * 32 + (((2 + hi) ^ vswz) * 8)];
      bf16x8 v11 = *(const bf16x8*)&Vts[(32 + ql) * 32 + (((2 + hi) ^ vswz) * 8)];
      o0 = __builtin_amdgcn_mfma_f32_32x32x16_bf16(c0.bf, v00, o0, 0, 0, 0);
      o1 = __builtin_amdgcn_mfma_f32_32x32x16_bf16(c0.bf, v01, o1, 0, 0, 0);
      den = __builtin_amdgcn_mfma_f32_32x32x16_bf16(c0.bf, ones.bf, den, 0, 0, 0);
      o0 = __builtin_amdgcn_mfma_f32_32x32x16_bf16(c1.bf, v10, o0, 0, 0, 0);
      o1 = __builtin_amdgcn_mfma_f32_32x32x16_bf16(c1.bf, v11, o1, 0, 0, 0);
      den = __builtin_amdgcn_mfma_f32_32x32x16_bf16(c1.bf, ones.bf, den, 0, 0, 0);
    }
    __builtin_amdgcn_s_setprio(0);

    __syncthreads();          // next tile landed; all waves done with cur
    cur ^= 1;
  }
#undef STAGE

  // 4-way merge of (o0,o1,den) through LDS (tiles dead). Scratch: 6 groups
  // (2 qg x 3 writers) x 64 lanes x 17 f32 = 26KB < Ks' 32KB.
  float* mrg = (float*)Ks;
  f32x16 om0 = o0, om1 = o1, dm = den;
#define MERGE(vec) do { \
    if (kgr > 0) { \
      float* sw = mrg + ((qg * 3 + (kgr - 1)) * 64 + lane) * 17; \
      _Pragma("unroll") for (int r = 0; r < 16; r++) sw[r] = (vec)[r]; \
    } \
    __syncthreads(); \
    if (kgr == 0) { \
      _Pragma("unroll") for (int ws = 0; ws < 3; ws++) { \
        float* s2 = mrg + ((qg * 3 + ws) * 64 + lane) * 17; \
        _Pragma("unroll") for (int r = 0; r < 16; r++) (vec)[r] += s2[r]; \
      } \
    } \
    __syncthreads(); \
  } while (0)
  MERGE(om0);
  MERGE(om1);
  MERGE(dm);
#undef MERGE

  if (kgr == 0) {
#pragma unroll
    for (int r = 0; r < 16; r++) {
      const int qo = (r & 3) + 8 * (r >> 2) + 4 * hi;
      const float iv = fast_rcp(dm[r]);
      const size_t orow = rowb + q0 + qg * 32 + qo;
      y[orow * 1024 + hc + ql]      = f2bf(om0[r] * iv);
      y[orow * 1024 + hc + 32 + ql] = f2bf(om1[r] * iv);
    }
  }
}

// --------------------------------------------------------------------------
extern "C" void kernel_launch(void* const* d_in, const int* in_sizes, int n_in,
                              void* d_out, int out_size, void* d_ws, size_t ws_size,
                              hipStream_t stream) {
  const float* x    = (const float*)d_in[0];  // (2,2048,1024) fp32
  const int* mask   = (const int*)d_in[1];    // (2,2048) int32
  const float* Wqkv = (const float*)d_in[2];  // (1024,1024) fp32
  const float* Wout = (const float*)d_in[3];  // (1024,1024) fp32
  const float* bout = (const float*)d_in[4];  // (1024,) fp32
  float* out = (float*)d_out;                 // (2,2048,1024) fp32

  u16* w     = (u16*)d_ws;                 // 4096*1024 bf16   (8 MB)
  u16* y     = w + 4096 * 1024;            // 4096*1024 bf16   (8 MB)
  u16* WqkvT = y + 4096 * 1024;            // 1024*1024 bf16   (2 MB)
  u16* WoutT = WqkvT + 1024 * 1024;        // 1024*1024 bf16   (2 MB)
  u16* Vt    = WoutT + 1024 * 1024;        // 32*64*2048 bf16  (8 MB)
  u16* xb    = y;                          // alias: y dead until attn writes it

  prep<<<dim3(16, 16, 10), dim3(16, 16), 0, stream>>>(x, xb, Wqkv, WqkvT, Wout, WoutT);
  gemm_bt<false><<<dim3(64, 16), 256, 0, stream>>>(xb, WqkvT, w, nullptr, 4096, 1024, 1024);
  scale_transpose_v<<<dim3(32, 1, 32), dim3(16, 16), 0, stream>>>(w, mask, Vt);
  attn_kernel<<<dim3(32, 32), 512, 0, stream>>>(w, Vt, y);
  gemm_bt<true><<<dim3(64, 16), 256, 0, stream>>>(y, WoutT, out, bout, 4096, 1024, 1024);
}

// Round 13
// 159.319 us; speedup vs baseline: 1.0448x; 1.0448x over previous
//
#include <hip/hip_runtime.h>
#include <hip/hip_bf16.h>
#include <stdint.h>

typedef unsigned short u16;
typedef unsigned int u32;
typedef __bf16 bf16x8 __attribute__((ext_vector_type(8)));
typedef float f32x4 __attribute__((ext_vector_type(4)));
typedef float f32x16 __attribute__((ext_vector_type(16)));
typedef u32 u32x4 __attribute__((ext_vector_type(4)));

#define AS1 __attribute__((address_space(1)))
#define AS3 __attribute__((address_space(3)))

// async global->LDS, 16B per lane; LDS dest = wave-uniform base + lane*16.
__device__ __forceinline__ void async16(const u16* g, u16* l) {
  __builtin_amdgcn_global_load_lds((const AS1 uint32_t*)(const void*)g,
                                   (AS3 uint32_t*)l, 16, 0, 0);
}

__device__ __forceinline__ u16 f2bf(float v) {
  union { __hip_bfloat16 b; u16 u; } c; c.b = __float2bfloat16(v); return c.u;
}

// hardware packed f32->bf16 (RNE), one VALU op per pair (T12)
__device__ __forceinline__ u32 pkbf(float a, float b) {
  u32 r;
  asm("v_cvt_pk_bf16_f32 %0, %1, %2" : "=v"(r) : "v"(a), "v"(b));
  return r;
}

// v_permlane32_swap_b32: a[32:63] <-> b[0:31]
__device__ __forceinline__ void swap32(u32 &a, u32 &b) {
  asm("v_permlane32_swap_b32 %0, %1" : "+v"(a), "+v"(b));
}

// raw v_exp_f32 — args here are in [-45,-15]: results normal, no OCML wrapper.
#if __has_builtin(__builtin_amdgcn_exp2f)
#define fast_exp2(x) __builtin_amdgcn_exp2f(x)
#else
#define fast_exp2(x) exp2f(x)
#endif

#if __has_builtin(__builtin_amdgcn_rcpf)
#define fast_rcp(x) __builtin_amdgcn_rcpf(x)
#else
#define fast_rcp(x) (1.0f / (x))
#endif

__device__ __forceinline__ uint4 pack8(float4 lo, float4 hi) {
  uint4 q;
  q.x = (u32)f2bf(lo.x) | ((u32)f2bf(lo.y) << 16);
  q.y = (u32)f2bf(lo.z) | ((u32)f2bf(lo.w) << 16);
  q.z = (u32)f2bf(hi.x) | ((u32)f2bf(hi.y) << 16);
  q.w = (u32)f2bf(hi.z) | ((u32)f2bf(hi.w) << 16);
  return q;
}

// ---------------- prep: fused {x cvt} + {Wqkv^T, Wout^T} ------------------
// (Round-8 version — passing.)
__global__ void prep(const float* __restrict__ x, u16* __restrict__ xb,
                     const float* __restrict__ Wqkv, u16* __restrict__ WqkvT,
                     const float* __restrict__ Wout, u16* __restrict__ WoutT) {
  const int tx = threadIdx.x, ty = threadIdx.y, z = blockIdx.z;
  if (z >= 2) {
    const int cid = (z - 2) * 256 + blockIdx.y * 16 + blockIdx.x;
    const int t = ty * 16 + tx;
    const int i = (cid * 256 + t) * 8;
    float4 lo = *(const float4*)(x + i);
    float4 hi = *(const float4*)(x + i + 4);
    *(uint4*)(xb + i) = pack8(lo, hi);
    return;
  }
  const float* in = z ? Wout : Wqkv;
  u16* out = z ? WoutT : WqkvT;
  __shared__ u16 tile[64][65];
  const int c0 = blockIdx.x * 64, r0 = blockIdx.y * 64;
#pragma unroll
  for (int i = 0; i < 4; i++) {
    const int row = r0 + ty + i * 16;
    float4 v = *(const float4*)&in[(size_t)row * 1024 + c0 + tx * 4];
    tile[tx * 4 + 0][ty + i * 16] = f2bf(v.x);
    tile[tx * 4 + 1][ty + i * 16] = f2bf(v.y);
    tile[tx * 4 + 2][ty + i * 16] = f2bf(v.z);
    tile[tx * 4 + 3][ty + i * 16] = f2bf(v.w);
  }
  __syncthreads();
#pragma unroll
  for (int i = 0; i < 4; i++) {
    const int orow = c0 + ty + i * 16;
    u32 w0 = (u32)tile[ty + i * 16][tx * 4 + 0] | ((u32)tile[ty + i * 16][tx * 4 + 1] << 16);
    u32 w1 = (u32)tile[ty + i * 16][tx * 4 + 2] | ((u32)tile[ty + i * 16][tx * 4 + 3] << 16);
    uint2 pk = {w0, w1};
    *(uint2*)&out[(size_t)orow * 1024 + r0 + tx * 4] = pk;
  }
}

// ---------------- build Vt[b][h][d][j] = mask[b][j] ? 0 : w[b,j][h*64+d] --
// (Round-8 version — passing.)
__global__ void scale_transpose_v(const u16* __restrict__ w, const int* __restrict__ mask,
                                  u16* __restrict__ Vt) {
  __shared__ u16 tile[64][65];
  const int tx = threadIdx.x, ty = threadIdx.y;
  const int j0 = blockIdx.x * 64;
  const int bh = blockIdx.z, b = bh >> 4, hc = (bh & 15) * 64;
#pragma unroll
  for (int i = 0; i < 4; i++) {
    const int j = j0 + ty + i * 16;
    uint2 v = *(const uint2*)&w[(size_t)(b * 2048 + j) * 1024 + hc + tx * 4];
    if (mask[b * 2048 + j]) { v.x = 0u; v.y = 0u; }
    tile[tx * 4 + 0][ty + i * 16] = (u16)(v.x & 0xFFFF);
    tile[tx * 4 + 1][ty + i * 16] = (u16)(v.x >> 16);
    tile[tx * 4 + 2][ty + i * 16] = (u16)(v.y & 0xFFFF);
    tile[tx * 4 + 3][ty + i * 16] = (u16)(v.y >> 16);
  }
  __syncthreads();
#pragma unroll
  for (int i = 0; i < 4; i++) {
    const int d = ty + i * 16;
    u32 w0 = (u32)tile[d][tx * 4 + 0] | ((u32)tile[d][tx * 4 + 1] << 16);
    u32 w1 = (u32)tile[d][tx * 4 + 2] | ((u32)tile[d][tx * 4 + 3] << 16);
    uint2 pk = {w0, w1};
    *(uint2*)&Vt[((size_t)bh * 64 + d) * 2048 + j0 + tx * 4] = pk;
  }
}

// ---------------- GEMM: C(MxN) = A(MxK) * BT(NxK)^T  [+bias], bf16 A/B ----
// Round-8 64x64 kernel with the T3 minimal SINGLE-barrier loop (catalog
// recipe): prologue stage+vmcnt(0)+barrier; per-iter STAGE(next) -> MFMA(cur)
// -> lgkmcnt(0) -> vmcnt(0) -> barrier. One barrier per K-step (was two).
// Safety: reads of buf_j covered by iter j-1's vmcnt(0)+barrier; restage of
// buf_j at iter j+1 is behind iter j's barrier (reads MFMA-consumed by then).
template<bool OUT_F32>
__launch_bounds__(256)
__global__ void gemm_bt(const u16* __restrict__ A, const u16* __restrict__ BT,
                        void* __restrict__ Cp, const float* __restrict__ bias,
                        int M, int N, int K) {
  __shared__ __align__(16) u16 As[2][64 * 64];    // 16 KB
  __shared__ __align__(16) u16 Bs[2][64 * 64];    // 16 KB
  const int t = threadIdx.x;
  const int lane = t & 63, wave = t >> 6;
  const int ql = lane & 31, hi = lane >> 5, swz = ql & 7;
  const int wgid = blockIdx.x + gridDim.x * blockIdx.y;
  const int c = wgid & 7, ii = wgid >> 3;
  const int m0 = (c * 8 + (ii & 7)) * 64;
  const int n0 = (ii >> 3) * 64;
  const int wm = (wave & 1) * 32, wn = (wave >> 1) * 32;

  f32x16 acc = {};

  const int sr = t >> 3;
  const int sc8 = ((t & 7) ^ (sr & 7)) * 8;
  const u16* gAt = A + (size_t)(m0 + sr) * K + sc8;
  const u16* gBt = BT + (size_t)(n0 + sr) * K + sc8;

#define GSTAGE(buf, k0s) do { \
    async16(gAt + (k0s),                   &As[buf][t * 8]); \
    async16(gAt + (k0s) + (size_t)32 * K,  &As[buf][t * 8 + 2048]); \
    async16(gBt + (k0s),                   &Bs[buf][t * 8]); \
    async16(gBt + (k0s) + (size_t)32 * K,  &Bs[buf][t * 8 + 2048]); \
  } while (0)

  // prologue: stage tile 0, drain, barrier
  GSTAGE(0, 0);
  asm volatile("s_waitcnt vmcnt(0)" ::: "memory");
  __builtin_amdgcn_s_barrier();
  __builtin_amdgcn_sched_barrier(0);   // rule #18

  int cur = 0;
  for (int k0 = 0; k0 < K; k0 += 64) {
    if (k0 + 64 < K) GSTAGE(cur ^ 1, k0 + 64);   // prefetch flies over MFMA phase

#pragma unroll
    for (int kk = 0; kk < 4; kk++) {
      bf16x8 af = *(const bf16x8*)&As[cur][(wm + ql) * 64 + (((2 * kk + hi) ^ swz) * 8)];
      bf16x8 bfr = *(const bf16x8*)&Bs[cur][(wn + ql) * 64 + (((2 * kk + hi) ^ swz) * 8)];
      acc = __builtin_amdgcn_mfma_f32_32x32x16_bf16(af, bfr, acc, 0, 0, 0);
    }
    asm volatile("s_waitcnt lgkmcnt(0)" ::: "memory");   // ds_reads of cur retired
    asm volatile("s_waitcnt vmcnt(0)" ::: "memory");     // next tile landed
    __builtin_amdgcn_sched_barrier(0);
    __builtin_amdgcn_s_barrier();                        // ONE barrier per K-step
    __builtin_amdgcn_sched_barrier(0);
    cur ^= 1;
  }
#undef GSTAGE

  const float bv = bias ? bias[n0 + wn + ql] : 0.f;
  const int col = n0 + wn + ql;

#pragma unroll
  for (int r = 0; r < 16; r++) {
    const int row = m0 + wm + (r & 3) + 8 * (r >> 2) + 4 * hi;
    const size_t ci = (size_t)row * N + col;
    const float v = acc[r] + bv;
    if (OUT_F32) ((float*)Cp)[ci] = v;
    else ((u16*)Cp)[ci] = f2bf(v);
  }
}

// ---------------- fused attention per (b,h) -------------------------------
// (Round-8 version — proven 46.7us. r9/r12 occupancy restructures both
// regressed; this structure is the measured optimum: grid 512 x 512thr,
// 4qg x 2kgr waves, KVBLK=64, 1 barrier/tile, MFMA denominator.)
#define C1 0.18033688f      // 0.125 * log2(e)
#define C2 -28.853901f      // -20 * log2(e)
__launch_bounds__(512)
__global__ void attn_kernel(const u16* __restrict__ w, const u16* __restrict__ Vt,
                            u16* __restrict__ y) {
  __shared__ __align__(16) u16 smem[2][2][2][64 * 64];
  const int t = threadIdx.x, lane = t & 63, wv = t >> 6;
  const int qg = wv & 3, kgr = wv >> 2;
  const int ql = lane & 31, hi = lane >> 5, swz = ql & 7;
  const int wgid = blockIdx.x + 16 * blockIdx.y;
  const int newid = (wgid & 7) * 64 + (wgid >> 3);
  const int bh = newid >> 4, b = bh >> 4, hc = (bh & 15) * 64;
  const int q0 = (newid & 15) * 128;
  const size_t rowb = (size_t)b * 2048;

  const int tt = t & 255;
  const int sg = t >> 8;
  const int skey = tt >> 3;
  const int scl = ((tt & 7) ^ (skey & 7)) * 8;
  const int sjb = sg * 1024;
  const u16* kptr = w + rowb * 1024 + hc;
  const u16* vptr = Vt + (size_t)bh * 64 * 2048;

  bf16x8 qf[4];
  {
    const size_t qrow = rowb + q0 + qg * 32 + ql;
#pragma unroll
    for (int ks = 0; ks < 4; ks++)
      qf[ks] = *(const bf16x8*)&w[qrow * 1024 + hc + ks * 16 + hi * 8];
  }

  union { u32x4 u; bf16x8 bf; } ones;
  ones.u = (u32x4){0x3F803F80u, 0x3F803F80u, 0x3F803F80u, 0x3F803F80u};

  f32x16 o0 = {}, o1 = {};
  f32x16 den = {};

#define STAGE(buf, j0s) do { \
    async16(kptr + (size_t)(sjb + (j0s) + skey) * 1024 + scl,       &smem[0][sg][buf][tt * 8]); \
    async16(kptr + (size_t)(sjb + (j0s) + skey + 32) * 1024 + scl,  &smem[0][sg][buf][2048 + tt * 8]); \
    async16(vptr + (size_t)skey * 2048 + sjb + (j0s) + scl,         &smem[1][sg][buf][tt * 8]); \
    async16(vptr + (size_t)(skey + 32) * 2048 + sjb + (j0s) + scl,  &smem[1][sg][buf][2048 + tt * 8]); \
  } while (0)

  STAGE(0, 0);
  __syncthreads();

  int cur = 0;
  for (int j0 = 0; j0 < 1024; j0 += 64) {
    if (j0 + 64 < 1024) STAGE(cur ^ 1, j0 + 64);

    const u16* Wt = smem[0][kgr][cur];
    const u16* Vts = smem[1][kgr][cur];

    u32x4 pa[4];
#pragma unroll
    for (int g = 0; g < 2; g++) {
      f32x16 p = {};
#pragma unroll
      for (int ks = 0; ks < 4; ks++) {
        bf16x8 af = *(const bf16x8*)
            &Wt[(g * 32 + ql) * 64 + (((ks * 2 + hi) ^ swz) * 8)];
        p = __builtin_amdgcn_mfma_f32_32x32x16_bf16(af, qf[ks], p, 0, 0, 0);
      }
      float e[16];
#pragma unroll
      for (int r = 0; r < 16; r++)
        e[r] = fast_exp2(fmaf(p[r], C1, C2));
      u32 a0 = pkbf(e[0], e[1]),   b0 = pkbf(e[4], e[5]);   swap32(a0, b0);
      u32 a1 = pkbf(e[2], e[3]),   b1 = pkbf(e[6], e[7]);   swap32(a1, b1);
      u32 a2 = pkbf(e[8], e[9]),   b2 = pkbf(e[12], e[13]); swap32(a2, b2);
      u32 a3 = pkbf(e[10], e[11]), b3 = pkbf(e[14], e[15]); swap32(a3, b3);
      u32x4 f0 = {a0, a1, b0, b1};
      u32x4 f1 = {a2, a3, b2, b3};
      pa[2 * g + 0] = f0;
      pa[2 * g + 1] = f1;
    }

    __builtin_amdgcn_s_setprio(1);
#pragma unroll
    for (int ks = 0; ks < 4; ks++) {
      union { u32x4 u; bf16x8 bf; } cv; cv.u = pa[ks];
      bf16x8 vb0 = *(const bf16x8*)
          &Vts[ql * 64 + (((ks * 2 + hi) ^ swz) * 8)];
      bf16x8 vb1 = *(const bf16x8*)
          &Vts[(32 + ql) * 64 + (((ks * 2 + hi) ^ swz) * 8)];
      o0 = __builtin_amdgcn_mfma_f32_32x32x16_bf16(cv.bf, vb0, o0, 0, 0, 0);
      o1 = __builtin_amdgcn_mfma_f32_32x32x16_bf16(cv.bf, vb1, o1, 0, 0, 0);
      den = __builtin_amdgcn_mfma_f32_32x32x16_bf16(cv.bf, ones.bf, den, 0, 0, 0);
    }
    __builtin_amdgcn_s_setprio(0);

    __syncthreads();
    cur ^= 1;
  }
#undef STAGE

  float* mrg = (float*)smem;
  float* slot = mrg + (qg * 64 + lane) * 49;
  if (kgr == 1) {
#pragma unroll
    for (int r = 0; r < 16; r++) {
      slot[r] = o0[r]; slot[16 + r] = o1[r]; slot[32 + r] = den[r];
    }
  }
  __syncthreads();
  if (kgr == 0) {
#pragma unroll
    for (int r = 0; r < 16; r++) {
      o0[r] += slot[r]; o1[r] += slot[16 + r]; den[r] += slot[32 + r];
    }
#pragma unroll
    for (int r = 0; r < 16; r++) {
      const int qo = (r & 3) + 8 * (r >> 2) + 4 * hi;
      const float iv = fast_rcp(den[r]);
      const size_t orow = rowb + q0 + qg * 32 + qo;
      y[orow * 1024 + hc + ql]      = f2bf(o0[r] * iv);
      y[orow * 1024 + hc + 32 + ql] = f2bf(o1[r] * iv);
    }
  }
}

// --------------------------------------------------------------------------
extern "C" void kernel_launch(void* const* d_in, const int* in_sizes, int n_in,
                              void* d_out, int out_size, void* d_ws, size_t ws_size,
                              hipStream_t stream) {
  const float* x    = (const float*)d_in[0];  // (2,2048,1024) fp32
  const int* mask   = (const int*)d_in[1];    // (2,2048) int32
  const float* Wqkv = (const float*)d_in[2];  // (1024,1024) fp32
  const float* Wout = (const float*)d_in[3];  // (1024,1024) fp32
  const float* bout = (const float*)d_in[4];  // (1024,) fp32
  float* out = (float*)d_out;                 // (2,2048,1024) fp32

  u16* w     = (u16*)d_ws;                 // 4096*1024 bf16   (8 MB)
  u16* y     = w + 4096 * 1024;            // 4096*1024 bf16   (8 MB)
  u16* WqkvT = y + 4096 * 1024;            // 1024*1024 bf16   (2 MB)
  u16* WoutT = WqkvT + 1024 * 1024;        // 1024*1024 bf16   (2 MB)
  u16* Vt    = WoutT + 1024 * 1024;        // 32*64*2048 bf16  (8 MB)
  u16* xb    = y;                          // alias: y dead until attn writes it

  prep<<<dim3(16, 16, 10), dim3(16, 16), 0, stream>>>(x, xb, Wqkv, WqkvT, Wout, WoutT);
  gemm_bt<false><<<dim3(64, 16), 256, 0, stream>>>(xb, WqkvT, w, nullptr, 4096, 1024, 1024);
  scale_transpose_v<<<dim3(32, 1, 32), dim3(16, 16), 0, stream>>>(w, mask, Vt);
  attn_kernel<<<dim3(16, 32), 512, 0, stream>>>(w, Vt, y);
  gemm_bt<true><<<dim3(64, 16), 256, 0, stream>>>(y, WoutT, out, bout, 4096, 1024, 1024);
}